// Round 12
// baseline (101.982 us; speedup 1.0000x reference)
//
#include <hip/hip_runtime.h>

#define N_ANCH 49104
#define NB_IMG 16
#define NGT 100
#define NC 80
#define BPI 96                 // blocks per image
#define APB 512                // anchors (rows) per block
#define RPW 128                // rows per wave
#define NBLK (BPI * NB_IMG)    // 1536
#define ROW_F4 (NC / 4)        // 20 float4 per row
#define WCH (RPW * ROW_F4)     // 2560 float4 per wave chunk
#define MAXG 104               // per-wave filtered GT capacity
#define NPF 8                  // prefetch depth (float4 per lane)

#define LOG2E 1.4426950408889634f
#define LN2   0.6931471805599453f
#define FSCALE (0.75f * LN2)

// compile-time f32 half-extents per (ratio,scale) pair k = rr*3 + sc
__constant__ float BW9[9] = {
  (float)(4.0               / 0.7071067811865476 * 0.5),
  (float)(5.039684199579493 / 0.7071067811865476 * 0.5),
  (float)(6.349604207872798 / 0.7071067811865476 * 0.5),
  (float)(4.0               * 0.5),
  (float)(5.039684199579493 * 0.5),
  (float)(6.349604207872798 * 0.5),
  (float)(4.0               / 1.4142135623730951 * 0.5),
  (float)(5.039684199579493 / 1.4142135623730951 * 0.5),
  (float)(6.349604207872798 / 1.4142135623730951 * 0.5),
};
__constant__ float BH9[9] = {
  (float)(4.0               * 0.7071067811865476 * 0.5),
  (float)(5.039684199579493 * 0.7071067811865476 * 0.5),
  (float)(6.349604207872798 * 0.7071067811865476 * 0.5),
  (float)(4.0               * 0.5),
  (float)(5.039684199579493 * 0.5),
  (float)(6.349604207872798 * 0.5),
  (float)(4.0               * 1.4142135623730951 * 0.5),
  (float)(5.039684199579493 * 1.4142135623730951 * 0.5),
  (float)(6.349604207872798 * 1.4142135623730951 * 0.5),
};

__device__ __forceinline__ float frcp(float x){ return __builtin_amdgcn_rcpf(x); }
__device__ __forceinline__ float fexp2(float x){ return __builtin_amdgcn_exp2f(x); }
__device__ __forceinline__ float flog2(float x){ return __builtin_amdgcn_logf(x); }

// p(x)^2 * softplus(x)/LN2  (caller scales by 0.75*LN2)
__device__ __forceinline__ float f0_term(float x){
  float xl = x * LOG2E;
  float mx = fmaxf(xl, 0.f);
  float mn = fminf(xl, 0.f);
  float u  = fexp2(mn - mx);      // e^{-|x|}
  float w  = 1.0f + u;
  float lw = flog2(w);
  float g  = mn - lw;             // log2(sigmoid)
  return fexp2(g + g) * (lw + mx);
}
__device__ __forceinline__ float f0x4(float4 c4){
  return (f0_term(c4.x) + f0_term(c4.y)) + (f0_term(c4.z) + f0_term(c4.w));
}

// (f1 - f0) correction for the one-hot label class (absolute units)
__device__ __forceinline__ float corr_term(float x){
  float xl = x * LOG2E;
  float mx = fmaxf(xl, 0.f);
  float mn = fminf(xl, 0.f);
  float u  = fexp2(mn - mx);
  float w  = 1.0f + u;
  float lw = flog2(w);
  float p2   = fexp2(2.f * (mn - lw));
  float omp2 = fexp2(-2.f * (mx + lw));
  float sp   = LN2 * (lw + mx);
  float spn  = LN2 * (lw - mn);
  return 0.25f * omp2 * spn - 0.75f * p2 * sp;
}

// f32 anchor geometry (table-based, no f64, no divides)
__device__ __forceinline__ void anchor_geom(int a, float& x1, float& y1,
                                            float& x2, float& y2){
  int lg, st, rel;
  if      (a < 36864){ lg = 6; st = 8;   rel = a; }
  else if (a < 46080){ lg = 5; st = 16;  rel = a - 36864; }
  else if (a < 48384){ lg = 4; st = 32;  rel = a - 46080; }
  else if (a < 48960){ lg = 3; st = 64;  rel = a - 48384; }
  else               { lg = 2; st = 128; rel = a - 48960; }
  int cell = rel / 9;
  int k    = rel - cell * 9;
  int yy   = cell >> lg;
  int xx   = cell & ((1 << lg) - 1);
  float stf = (float)st;
  float cx = ((float)xx + 0.5f) * stf;   // exact in f32
  float cy = ((float)yy + 0.5f) * stf;
  float w2 = stf * BW9[k];               // exact scaling of correctly-rounded base
  float h2 = stf * BH9[k];
  x1 = cx - w2; y1 = cy - h2; x2 = cx + w2; y2 = cy + h2;
}

__global__ __launch_bounds__(256, 6) void fused_loss_kernel(
    const float* __restrict__ cls,
    const float* __restrict__ bbox,
    const float* __restrict__ gtb,
    const int*   __restrict__ gtl,
    const unsigned char* __restrict__ gmask,
    float* __restrict__ S,        // [48]: c[16], bb[16], p[16] (zeroed each call)
    int*   __restrict__ ctr,      // [1]  arrival counter (zeroed each call)
    float* __restrict__ out)      // [2]  final losses
{
  const int tid = threadIdx.x;
  const int wv = tid >> 6, ln = tid & 63;
  const int b  = blockIdx.y;
  const int a0 = blockIdx.x * APB;
  const int nvalid = min(N_ANCH - a0, APB);
  const int nf4 = nvalid * ROW_F4;
  const int wb  = wv * WCH;                       // wave chunk base (float4)
  const int jend = min(WCH, nf4 - wb);            // >= 1600 always
  const int rbase = wv * RPW;                     // wave's first block-row

  __shared__ float4 s_cgt[4][MAXG];
  __shared__ float  s_carea[4][MAXG];
  __shared__ int    s_clab[4][MAXG];
  __shared__ float  s_wf[APB];     // row weight; wave-private slices, no barrier
  __shared__ float  s_r0[4], s_r1[4], s_r2[4];

  const float* clsbase = cls + (size_t)(b * N_ANCH + a0) * NC;
  const float4* cp = (const float4*)clsbase;

  // ---- prefetch first NPF stream iterations of THIS WAVE's chunk (t ~ 0) ----
  float4 pf[NPF];
  #pragma unroll
  for (int k = 0; k < NPF; ++k) pf[k] = cp[wb + ln + k * 64];   // 512 <= 1600 safe

  // ---- f32 geometry for this lane's 2 rows (wave-owned rows) ----
  float ax1[2], ay1[2], ax2[2], ay2[2];
  #pragma unroll
  for (int r = 0; r < 2; ++r){
    int a = a0 + rbase + 2 * ln + r;
    if (a < N_ANCH) anchor_geom(a, ax1[r], ay1[r], ax2[r], ay2[r]);
    else { ax1[r] = 0.f; ay1[r] = 3.0e38f; ax2[r] = 0.f; ay2[r] = -3.0e38f; }
  }

  // ---- per-wave y-extent over its own 128 rows (tight; no LDS/barrier) ----
  float ymin = fminf(ay1[0], ay1[1]);
  float ymax = fmaxf(ay2[0], ay2[1]);
  #pragma unroll
  for (int o = 32; o > 0; o >>= 1){
    ymin = fminf(ymin, __shfl_xor(ymin, o));
    ymax = fmaxf(ymax, __shfl_xor(ymax, o));
  }

  // ---- mask layout detection (per wave; bool8 vs int32 vs float32) ----
  const unsigned int* mw = (const unsigned int*)gmask;
  bool nfb = false, ob = false;
  for (int i = ln; i < (NB_IMG * NGT) / 4; i += 64){
    unsigned int w = mw[i];
    nfb |= (w != 0u && w != 0x3F800000u);
    ob  |= ((w & 0xFFFFFF00u) != 0u);
  }
  const bool byteLayout = __any((int)nfb) && __any((int)ob);

  // ---- per-wave GT y-filter + ordered compaction (own LDS region) ----
  const float4* g4 = (const float4*)gtb;
  float4 g = g4[b * NGT + ln];
  int v = byteLayout ? (gmask[b * NGT + ln] != 0)
                     : (((const unsigned int*)gmask)[b * NGT + ln] != 0u);
  bool pass = v && (g.y < ymax) && (g.w > ymin);   // exact: fail => IoU == 0
  unsigned long long bal = __ballot(pass);
  int pre = __popcll(bal & ((1ull << ln) - 1ull));
  if (pass){
    s_cgt[wv][pre]   = g;
    s_carea[wv][pre] = (g.z - g.x) * (g.w - g.y);
    s_clab[wv][pre]  = gtl[b * NGT + ln];
  }
  int cnt = __popcll(bal);
  float4 g1; bool pass1 = false;
  if (ln < NGT - 64){
    g1 = g4[b * NGT + 64 + ln];
    int v1 = byteLayout ? (gmask[b * NGT + 64 + ln] != 0)
                        : (((const unsigned int*)gmask)[b * NGT + 64 + ln] != 0u);
    pass1 = v1 && (g1.y < ymax) && (g1.w > ymin);
  }
  unsigned long long bal1 = __ballot(pass1);
  int pre1 = cnt + __popcll(bal1 & ((1ull << ln) - 1ull));
  if (pass1){
    s_cgt[wv][pre1]   = g1;
    s_carea[wv][pre1] = (g1.z - g1.x) * (g1.w - g1.y);
    s_clab[wv][pre1]  = gtl[b * NGT + 64 + ln];
  }
  cnt += __popcll(bal1);
  if (ln == 0){
    float4 far4; far4.x = 3e9f; far4.y = 3e9f; far4.z = 3e9f; far4.w = 3e9f;
    s_cgt[wv][cnt]   = far4; s_carea[wv][cnt]   = 0.f; s_clab[wv][cnt]   = 0;
    s_cgt[wv][cnt+1] = far4; s_carea[wv][cnt+1] = 0.f; s_clab[wv][cnt+1] = 0;
  }
  const int cntp = (cnt + 1) & ~1;   // even; 0 if cnt==0

  // ---- IoU argmax + SmoothL1 + pos corr for this lane's 2 rows ----
  float accB = 0.f, posf = 0.f, fcorr = 0.f;
  #pragma unroll
  for (int r = 0; r < 2; ++r){
    int row = rbase + 2 * ln + r;
    int a = a0 + row;
    float x1 = ax1[r], y1 = ay1[r], x2 = ax2[r], y2 = ay2[r];
    float areaA = (x2 - x1) * (y2 - y1);
    // division-free argmax (R2-verified): compare I*Ub > Ib*U
    float Ib = -1.f, Ub = 1.f; int best = 0;
    for (int j = 0; j < cntp; j += 2){
      #pragma unroll
      for (int u2 = 0; u2 < 2; ++u2){
        int jj = j + u2;
        float4 gg = s_cgt[wv][jj];
        float lx = fmaxf(x1, gg.x), ly = fmaxf(y1, gg.y);
        float rx = fminf(x2, gg.z), ry = fminf(y2, gg.w);
        float iw = fmaxf(rx - lx, 0.f), ih = fmaxf(ry - ly, 0.f);
        float I  = iw * ih;
        float U  = (areaA + s_carea[wv][jj]) - I;
        bool gt = I * Ub > Ib * U;
        best = gt ? jj : best;
        Ib = gt ? I : Ib;
        Ub = gt ? U : Ub;
      }
    }
    bool va  = a < N_ANCH;
    bool pos = va && (2.f * Ib >= Ub);               // iou >= 0.5
    bool ign = va && !pos && (5.f * Ib >= 2.f * Ub); // 0.4 <= iou < 0.5
    s_wf[row] = ign ? 0.f : 1.f;                     // wave-private slice

    if (pos){
      posf += 1.f;
      float4 gg = s_cgt[wv][best];
      float aw = x2 - x1, ah = y2 - y1;
      float axc = (x1 + x2) * 0.5f, ayc = (y1 + y2) * 0.5f;
      float gw = fmaxf(gg.z - gg.x, 1e-6f), gh = fmaxf(gg.w - gg.y, 1e-6f);
      float gxc = (gg.x + gg.z) * 0.5f, gyc = (gg.y + gg.w) * 0.5f;
      float t0 = (gxc - axc) / aw, t1 = (gyc - ayc) / ah;
      float t2 = LN2 * flog2(gw * frcp(aw));
      float t3 = LN2 * flog2(gh * frcp(ah));
      float4 bp = ((const float4*)bbox)[(size_t)b * N_ANCH + a];
      const float BETA = 1.0f / 9.0f;
      float d0 = fabsf(bp.x - t0), d1 = fabsf(bp.y - t1);
      float d2 = fabsf(bp.z - t2), d3 = fabsf(bp.w - t3);
      accB += (d0 < BETA) ? 4.5f * d0 * d0 : d0 - 0.5f * BETA;
      accB += (d1 < BETA) ? 4.5f * d1 * d1 : d1 - 0.5f * BETA;
      accB += (d2 < BETA) ? 4.5f * d2 * d2 : d2 - 0.5f * BETA;
      accB += (d3 < BETA) ? 4.5f * d3 * d3 : d3 - 0.5f * BETA;
      // (f1 - f0) at the label class (rare scattered dword)
      int lab = s_clab[wv][best];
      fcorr += corr_term(clsbase[(size_t)row * NC + lab]);
    }
  }
  // no __syncthreads: this wave reads only its own s_wf slice

  // ---- weighted f0 stream over THIS WAVE's contiguous chunk ----
  float fr0 = 0.f, fr1 = 0.f, fr2 = 0.f, fr3 = 0.f;
  #pragma unroll
  for (int k = 0; k < NPF; ++k){
    int j = ln + k * 64;
    float t = fmaf(s_wf[rbase + j / 20], f0x4(pf[k]), 0.f);
    if ((k & 3) == 0) fr0 += t; else if ((k & 3) == 1) fr1 += t;
    else if ((k & 3) == 2) fr2 += t; else fr3 += t;
  }
  int j = NPF * 64 + ln;
  for (; j + 192 < jend; j += 256){
    float4 c0 = cp[wb + j];
    float4 c1 = cp[wb + j + 64];
    float4 c2 = cp[wb + j + 128];
    float4 c3 = cp[wb + j + 192];
    fr0 = fmaf(s_wf[rbase + j / 20],         f0x4(c0), fr0);
    fr1 = fmaf(s_wf[rbase + (j + 64) / 20],  f0x4(c1), fr1);
    fr2 = fmaf(s_wf[rbase + (j + 128) / 20], f0x4(c2), fr2);
    fr3 = fmaf(s_wf[rbase + (j + 192) / 20], f0x4(c3), fr3);
  }
  for (; j < jend; j += 64){
    float4 c4 = cp[wb + j];
    fr0 = fmaf(s_wf[rbase + j / 20], f0x4(c4), fr0);
  }
  float accC = fmaf(FSCALE, (fr0 + fr1) + (fr2 + fr3), fcorr);

  // ---- block reduction (single barrier of the kernel) ----
  #pragma unroll
  for (int o = 32; o > 0; o >>= 1){
    accC += __shfl_down(accC, o);
    accB += __shfl_down(accB, o);
    posf += __shfl_down(posf, o);
  }
  if (ln == 0){ s_r0[wv] = accC; s_r1[wv] = accB; s_r2[wv] = posf; }
  __syncthreads();

  // ---- fused finalize: per-image atomics + last-block epilogue ----
  if (tid == 0){
    float c  = s_r0[0] + s_r0[1] + s_r0[2] + s_r0[3];
    float bb = s_r1[0] + s_r1[1] + s_r1[2] + s_r1[3];
    float p  = s_r2[0] + s_r2[1] + s_r2[2] + s_r2[3];
    atomicAdd(&S[b], c);
    atomicAdd(&S[NB_IMG + b], bb);
    atomicAdd(&S[2 * NB_IMG + b], p);
    __threadfence();
    int old = atomicAdd(ctr, 1);
    if (old == NBLK - 1){
      __threadfence();
      float lc = 0.f, lb = 0.f;
      #pragma unroll
      for (int i2 = 0; i2 < NB_IMG; ++i2){
        float cc = __hip_atomic_load(&S[i2],              __ATOMIC_RELAXED, __HIP_MEMORY_SCOPE_AGENT);
        float bv = __hip_atomic_load(&S[NB_IMG + i2],     __ATOMIC_RELAXED, __HIP_MEMORY_SCOPE_AGENT);
        float pv = __hip_atomic_load(&S[2 * NB_IMG + i2], __ATOMIC_RELAXED, __HIP_MEMORY_SCOPE_AGENT);
        float tot = fmaxf(pv, 1.f);
        lc += cc / tot;
        lb += bv / tot;
      }
      out[0] = lc / 16.f;
      out[1] = 10.f * lb / 16.f;
    }
  }
}

extern "C" void kernel_launch(void* const* d_in, const int* in_sizes, int n_in,
                              void* d_out, int out_size, void* d_ws, size_t ws_size,
                              hipStream_t stream) {
  const float* cls  = (const float*)d_in[0];
  const float* bbox = (const float*)d_in[1];
  const float* gtb  = (const float*)d_in[2];
  const int*   gtl  = (const int*)d_in[3];
  const unsigned char* gmask = (const unsigned char*)d_in[4];

  float* S   = (float*)d_ws;              // 48 floats
  int*   ctr = (int*)(S + 3 * NB_IMG);    // 1 int

  // zero the tiny accumulator block every call (graph-safe async memset)
  hipMemsetAsync(d_ws, 0, (3 * NB_IMG + 1) * sizeof(float), stream);

  dim3 grid(BPI, NB_IMG);
  fused_loss_kernel<<<grid, 256, 0, stream>>>(cls, bbox, gtb, gtl, gmask,
                                              S, ctr, (float*)d_out);
}

// Round 13
// 53.783 us; speedup vs baseline: 1.8962x; 1.8962x over previous
//
#include <hip/hip_runtime.h>

#define N_ANCH 49104
#define NB_IMG 16
#define NGT 100
#define NC 80
#define BPI 96                 // blocks per image
#define APB 512                // anchors (rows) per block
#define RPW 128                // rows per wave
#define NBLK (BPI * NB_IMG)    // 1536
#define ROW_F4 (NC / 4)        // 20 float4 per row
#define WCH (RPW * ROW_F4)     // 2560 float4 per wave chunk
#define MAXG 104               // per-wave filtered GT capacity
#define NPF 6                  // prefetch depth (float4 per lane)

#define LOG2E 1.4426950408889634f
#define LN2   0.6931471805599453f
#define FSCALE (0.75f * LN2)

// compile-time f32 half-extents per (ratio,scale) pair k = rr*3 + sc
__constant__ float BW9[9] = {
  (float)(4.0               / 0.7071067811865476 * 0.5),
  (float)(5.039684199579493 / 0.7071067811865476 * 0.5),
  (float)(6.349604207872798 / 0.7071067811865476 * 0.5),
  (float)(4.0               * 0.5),
  (float)(5.039684199579493 * 0.5),
  (float)(6.349604207872798 * 0.5),
  (float)(4.0               / 1.4142135623730951 * 0.5),
  (float)(5.039684199579493 / 1.4142135623730951 * 0.5),
  (float)(6.349604207872798 / 1.4142135623730951 * 0.5),
};
__constant__ float BH9[9] = {
  (float)(4.0               * 0.7071067811865476 * 0.5),
  (float)(5.039684199579493 * 0.7071067811865476 * 0.5),
  (float)(6.349604207872798 * 0.7071067811865476 * 0.5),
  (float)(4.0               * 0.5),
  (float)(5.039684199579493 * 0.5),
  (float)(6.349604207872798 * 0.5),
  (float)(4.0               * 1.4142135623730951 * 0.5),
  (float)(5.039684199579493 * 1.4142135623730951 * 0.5),
  (float)(6.349604207872798 * 1.4142135623730951 * 0.5),
};

__device__ __forceinline__ float frcp(float x){ return __builtin_amdgcn_rcpf(x); }
__device__ __forceinline__ float fexp2(float x){ return __builtin_amdgcn_exp2f(x); }
__device__ __forceinline__ float flog2(float x){ return __builtin_amdgcn_logf(x); }

// p(x)^2 * softplus(x)/LN2  (caller scales by 0.75*LN2)
__device__ __forceinline__ float f0_term(float x){
  float xl = x * LOG2E;
  float mx = fmaxf(xl, 0.f);
  float mn = fminf(xl, 0.f);
  float u  = fexp2(mn - mx);      // e^{-|x|}
  float w  = 1.0f + u;
  float lw = flog2(w);
  float g  = mn - lw;             // log2(sigmoid)
  return fexp2(g + g) * (lw + mx);
}
__device__ __forceinline__ float f0x4(float4 c4){
  return (f0_term(c4.x) + f0_term(c4.y)) + (f0_term(c4.z) + f0_term(c4.w));
}

// (f1 - f0) correction for the one-hot label class (absolute units)
__device__ __forceinline__ float corr_term(float x){
  float xl = x * LOG2E;
  float mx = fmaxf(xl, 0.f);
  float mn = fminf(xl, 0.f);
  float u  = fexp2(mn - mx);
  float w  = 1.0f + u;
  float lw = flog2(w);
  float p2   = fexp2(2.f * (mn - lw));
  float omp2 = fexp2(-2.f * (mx + lw));
  float sp   = LN2 * (lw + mx);
  float spn  = LN2 * (lw - mn);
  return 0.25f * omp2 * spn - 0.75f * p2 * sp;
}

// f32 anchor geometry (table-based, no f64, no divides)
__device__ __forceinline__ void anchor_geom(int a, float& x1, float& y1,
                                            float& x2, float& y2){
  int lg, st, rel;
  if      (a < 36864){ lg = 6; st = 8;   rel = a; }
  else if (a < 46080){ lg = 5; st = 16;  rel = a - 36864; }
  else if (a < 48384){ lg = 4; st = 32;  rel = a - 46080; }
  else if (a < 48960){ lg = 3; st = 64;  rel = a - 48384; }
  else               { lg = 2; st = 128; rel = a - 48960; }
  int cell = rel / 9;
  int k    = rel - cell * 9;
  int yy   = cell >> lg;
  int xx   = cell & ((1 << lg) - 1);
  float stf = (float)st;
  float cx = ((float)xx + 0.5f) * stf;   // exact in f32
  float cy = ((float)yy + 0.5f) * stf;
  float w2 = stf * BW9[k];               // exact scaling of correctly-rounded base
  float h2 = stf * BH9[k];
  x1 = cx - w2; y1 = cy - h2; x2 = cx + w2; y2 = cy + h2;
}

__global__ __launch_bounds__(256, 6) void fused_loss_kernel(
    const float* __restrict__ cls,
    const float* __restrict__ bbox,
    const float* __restrict__ gtb,
    const int*   __restrict__ gtl,
    const unsigned char* __restrict__ gmask,
    float* __restrict__ ws)
{
  const int tid = threadIdx.x;
  const int wv = tid >> 6, ln = tid & 63;
  const int b  = blockIdx.y;
  const int a0 = blockIdx.x * APB;
  const int bid = b * BPI + blockIdx.x;
  const int nvalid = min(N_ANCH - a0, APB);
  const int nf4 = nvalid * ROW_F4;
  const int wb  = wv * WCH;                       // wave chunk base (float4)
  const int jend = min(WCH, nf4 - wb);            // >= 1600 always
  const int rbase = wv * RPW;                     // wave's first block-row

  __shared__ float4 s_cgt[4][MAXG];
  __shared__ float  s_carea[4][MAXG];
  __shared__ int    s_clab[4][MAXG];
  __shared__ float  s_wf[APB];     // row weight; wave-private slices, no barrier
  __shared__ float  s_r0[4], s_r1[4], s_r2[4];

  const float* clsbase = cls + (size_t)(b * N_ANCH + a0) * NC;
  const float4* cp = (const float4*)clsbase;

  // ---- prefetch first NPF stream iterations of THIS WAVE's chunk (t ~ 0) ----
  float4 pf[NPF];
  #pragma unroll
  for (int k = 0; k < NPF; ++k) pf[k] = cp[wb + ln + k * 64];   // 384 < 1600 safe

  // ---- f32 geometry for this lane's 2 rows (wave-owned rows) ----
  float ax1[2], ay1[2], ax2[2], ay2[2];
  #pragma unroll
  for (int r = 0; r < 2; ++r){
    int a = a0 + rbase + 2 * ln + r;
    if (a < N_ANCH) anchor_geom(a, ax1[r], ay1[r], ax2[r], ay2[r]);
    else { ax1[r] = 0.f; ay1[r] = 3.0e38f; ax2[r] = 0.f; ay2[r] = -3.0e38f; }
  }

  // ---- per-wave y-extent over its own 128 rows (tight; no LDS/barrier) ----
  float ymin = fminf(ay1[0], ay1[1]);
  float ymax = fmaxf(ay2[0], ay2[1]);
  #pragma unroll
  for (int o = 32; o > 0; o >>= 1){
    ymin = fminf(ymin, __shfl_xor(ymin, o));
    ymax = fmaxf(ymax, __shfl_xor(ymax, o));
  }

  // ---- mask layout detection (per wave; bool8 vs int32 vs float32) ----
  const unsigned int* mw = (const unsigned int*)gmask;
  bool nfb = false, ob = false;
  for (int i = ln; i < (NB_IMG * NGT) / 4; i += 64){
    unsigned int w = mw[i];
    nfb |= (w != 0u && w != 0x3F800000u);
    ob  |= ((w & 0xFFFFFF00u) != 0u);
  }
  const bool byteLayout = __any((int)nfb) && __any((int)ob);

  // ---- per-wave GT y-filter + ordered compaction (own LDS region) ----
  const float4* g4 = (const float4*)gtb;
  float4 g = g4[b * NGT + ln];
  int v = byteLayout ? (gmask[b * NGT + ln] != 0)
                     : (((const unsigned int*)gmask)[b * NGT + ln] != 0u);
  bool pass = v && (g.y < ymax) && (g.w > ymin);   // exact: fail => IoU == 0
  unsigned long long bal = __ballot(pass);
  int pre = __popcll(bal & ((1ull << ln) - 1ull));
  if (pass){
    s_cgt[wv][pre]   = g;
    s_carea[wv][pre] = (g.z - g.x) * (g.w - g.y);
    s_clab[wv][pre]  = gtl[b * NGT + ln];
  }
  int cnt = __popcll(bal);
  float4 g1; bool pass1 = false;
  if (ln < NGT - 64){
    g1 = g4[b * NGT + 64 + ln];
    int v1 = byteLayout ? (gmask[b * NGT + 64 + ln] != 0)
                        : (((const unsigned int*)gmask)[b * NGT + 64 + ln] != 0u);
    pass1 = v1 && (g1.y < ymax) && (g1.w > ymin);
  }
  unsigned long long bal1 = __ballot(pass1);
  int pre1 = cnt + __popcll(bal1 & ((1ull << ln) - 1ull));
  if (pass1){
    s_cgt[wv][pre1]   = g1;
    s_carea[wv][pre1] = (g1.z - g1.x) * (g1.w - g1.y);
    s_clab[wv][pre1]  = gtl[b * NGT + 64 + ln];
  }
  cnt += __popcll(bal1);
  if (ln == 0){
    float4 far4; far4.x = 3e9f; far4.y = 3e9f; far4.z = 3e9f; far4.w = 3e9f;
    s_cgt[wv][cnt]   = far4; s_carea[wv][cnt]   = 0.f; s_clab[wv][cnt]   = 0;
    s_cgt[wv][cnt+1] = far4; s_carea[wv][cnt+1] = 0.f; s_clab[wv][cnt+1] = 0;
  }
  const int cntp = (cnt + 1) & ~1;   // even; 0 if cnt==0

  // ---- IoU argmax + SmoothL1 + pos corr for this lane's 2 rows ----
  float accB = 0.f, posf = 0.f, fcorr = 0.f;
  #pragma unroll
  for (int r = 0; r < 2; ++r){
    int row = rbase + 2 * ln + r;
    int a = a0 + row;
    float x1 = ax1[r], y1 = ay1[r], x2 = ax2[r], y2 = ay2[r];
    float areaA = (x2 - x1) * (y2 - y1);
    // division-free argmax (R2-verified): compare I*Ub > Ib*U
    float Ib = -1.f, Ub = 1.f; int best = 0;
    for (int j = 0; j < cntp; j += 2){
      #pragma unroll
      for (int u2 = 0; u2 < 2; ++u2){
        int jj = j + u2;
        float4 gg = s_cgt[wv][jj];
        float lx = fmaxf(x1, gg.x), ly = fmaxf(y1, gg.y);
        float rx = fminf(x2, gg.z), ry = fminf(y2, gg.w);
        float iw = fmaxf(rx - lx, 0.f), ih = fmaxf(ry - ly, 0.f);
        float I  = iw * ih;
        float U  = (areaA + s_carea[wv][jj]) - I;
        bool gt = I * Ub > Ib * U;
        best = gt ? jj : best;
        Ib = gt ? I : Ib;
        Ub = gt ? U : Ub;
      }
    }
    bool va  = a < N_ANCH;
    bool pos = va && (2.f * Ib >= Ub);               // iou >= 0.5
    bool ign = va && !pos && (5.f * Ib >= 2.f * Ub); // 0.4 <= iou < 0.5
    s_wf[row] = ign ? 0.f : 1.f;                     // wave-private slice

    if (pos){
      posf += 1.f;
      float4 gg = s_cgt[wv][best];
      float aw = x2 - x1, ah = y2 - y1;
      float axc = (x1 + x2) * 0.5f, ayc = (y1 + y2) * 0.5f;
      float gw = fmaxf(gg.z - gg.x, 1e-6f), gh = fmaxf(gg.w - gg.y, 1e-6f);
      float gxc = (gg.x + gg.z) * 0.5f, gyc = (gg.y + gg.w) * 0.5f;
      float t0 = (gxc - axc) / aw, t1 = (gyc - ayc) / ah;
      float t2 = LN2 * flog2(gw * frcp(aw));
      float t3 = LN2 * flog2(gh * frcp(ah));
      float4 bp = ((const float4*)bbox)[(size_t)b * N_ANCH + a];
      const float BETA = 1.0f / 9.0f;
      float d0 = fabsf(bp.x - t0), d1 = fabsf(bp.y - t1);
      float d2 = fabsf(bp.z - t2), d3 = fabsf(bp.w - t3);
      accB += (d0 < BETA) ? 4.5f * d0 * d0 : d0 - 0.5f * BETA;
      accB += (d1 < BETA) ? 4.5f * d1 * d1 : d1 - 0.5f * BETA;
      accB += (d2 < BETA) ? 4.5f * d2 * d2 : d2 - 0.5f * BETA;
      accB += (d3 < BETA) ? 4.5f * d3 * d3 : d3 - 0.5f * BETA;
      // (f1 - f0) at the label class (rare scattered dword)
      int lab = s_clab[wv][best];
      fcorr += corr_term(clsbase[(size_t)row * NC + lab]);
    }
  }
  // no __syncthreads: this wave reads only its own s_wf slice (LDS is
  // in-order within a wave; indices are opaque so compiler keeps order)

  // ---- weighted f0 stream over THIS WAVE's contiguous chunk ----
  float fr0 = 0.f, fr1 = 0.f, fr2 = 0.f, fr3 = 0.f;
  #pragma unroll
  for (int k = 0; k < NPF; ++k){
    int j = ln + k * 64;
    float t = fmaf(s_wf[rbase + j / 20], f0x4(pf[k]), 0.f);
    if ((k & 3) == 0) fr0 += t; else if ((k & 3) == 1) fr1 += t;
    else if ((k & 3) == 2) fr2 += t; else fr3 += t;
  }
  int j = NPF * 64 + ln;
  for (; j + 192 < jend; j += 256){
    float4 c0 = cp[wb + j];
    float4 c1 = cp[wb + j + 64];
    float4 c2 = cp[wb + j + 128];
    float4 c3 = cp[wb + j + 192];
    fr0 = fmaf(s_wf[rbase + j / 20],         f0x4(c0), fr0);
    fr1 = fmaf(s_wf[rbase + (j + 64) / 20],  f0x4(c1), fr1);
    fr2 = fmaf(s_wf[rbase + (j + 128) / 20], f0x4(c2), fr2);
    fr3 = fmaf(s_wf[rbase + (j + 192) / 20], f0x4(c3), fr3);
  }
  for (; j < jend; j += 64){
    float4 c4 = cp[wb + j];
    fr0 = fmaf(s_wf[rbase + j / 20], f0x4(c4), fr0);
  }
  float accC = fmaf(FSCALE, (fr0 + fr1) + (fr2 + fr3), fcorr);

  // ---- block reduction (single barrier of the kernel) ----
  #pragma unroll
  for (int o = 32; o > 0; o >>= 1){
    accC += __shfl_down(accC, o);
    accB += __shfl_down(accB, o);
    posf += __shfl_down(posf, o);
  }
  if (ln == 0){ s_r0[wv] = accC; s_r1[wv] = accB; s_r2[wv] = posf; }
  __syncthreads();
  if (tid == 0){
    ws[bid]            = s_r0[0] + s_r0[1] + s_r0[2] + s_r0[3];
    ws[NBLK + bid]     = s_r1[0] + s_r1[1] + s_r1[2] + s_r1[3];
    ws[2 * NBLK + bid] = s_r2[0] + s_r2[1] + s_r2[2] + s_r2[3];
  }
}

__global__ void finalize_kernel(const float* __restrict__ ws,
                                float* __restrict__ out)
{
  __shared__ float sC[NB_IMG], sB[NB_IMG];
  const int tid = threadIdx.x;          // 512 threads = 8 waves
  const int wv = tid >> 6, ln = tid & 63;
  #pragma unroll
  for (int i = 0; i < 2; ++i){
    int b = wv * 2 + i;
    float c = 0.f, bb = 0.f, p = 0.f;
    for (int k = ln; k < BPI; k += 64){
      c  += ws[b * BPI + k];
      bb += ws[NBLK + b * BPI + k];
      p  += ws[2 * NBLK + b * BPI + k];
    }
    #pragma unroll
    for (int o = 32; o > 0; o >>= 1){
      c += __shfl_down(c, o); bb += __shfl_down(bb, o); p += __shfl_down(p, o);
    }
    if (ln == 0){
      float tot = fmaxf(p, 1.f);
      sC[b] = c / tot;
      sB[b] = bb / tot;
    }
  }
  __syncthreads();
  if (tid == 0){
    float lc = 0.f, lb = 0.f;
    #pragma unroll
    for (int b = 0; b < NB_IMG; ++b){ lc += sC[b]; lb += sB[b]; }
    out[0] = lc / 16.f;
    out[1] = 10.f * lb / 16.f;
  }
}

extern "C" void kernel_launch(void* const* d_in, const int* in_sizes, int n_in,
                              void* d_out, int out_size, void* d_ws, size_t ws_size,
                              hipStream_t stream) {
  const float* cls  = (const float*)d_in[0];
  const float* bbox = (const float*)d_in[1];
  const float* gtb  = (const float*)d_in[2];
  const int*   gtl  = (const int*)d_in[3];
  const unsigned char* gmask = (const unsigned char*)d_in[4];

  float* ws = (float*)d_ws;   // 3*NBLK floats, fully overwritten every call

  dim3 grid(BPI, NB_IMG);
  fused_loss_kernel<<<grid, 256, 0, stream>>>(cls, bbox, gtb, gtl, gmask, ws);
  finalize_kernel<<<1, 512, 0, stream>>>(ws, (float*)d_out);
}